// Round 1
// baseline (719.127 us; speedup 1.0000x reference)
//
#include <hip/hip_runtime.h>

#define V_NODES 327696
#define E_EDGES 1966080
#define C_DIM   64
#define G_NUM   4
#define EPS_GN  1e-5f

// ---- monotonic float <-> uint encoding for atomicMax on floats ----
__device__ __forceinline__ unsigned enc_f(float f) {
    unsigned u = __float_as_uint(f);
    return u ^ ((u >> 31) ? 0xFFFFFFFFu : 0x80000000u);
}
__device__ __forceinline__ float dec_f(unsigned u) {
    unsigned v = u ^ ((u >> 31) ? 0x80000000u : 0xFFFFFFFFu);
    return __uint_as_float(v);
}

// ---------------------------------------------------------------------------
// Kernel 1: per-(graph,channel) sum / sumsq / count over x
// ---------------------------------------------------------------------------
__global__ __launch_bounds__(256) void k_stats1(const float* __restrict__ x,
                                                const int* __restrict__ batch,
                                                float* __restrict__ sum1,
                                                float* __restrict__ sumsq1,
                                                float* __restrict__ cnt) {
    int lane = threadIdx.x & 63;
    int wid  = threadIdx.x >> 6;
    float s0=0,s1=0,s2=0,s3=0,q0=0,q1=0,q2=0,q3=0;
    float c0=0,c1=0,c2=0,c3=0;
    int stride = gridDim.x * 4;
    for (int v = blockIdx.x * 4 + wid; v < V_NODES; v += stride) {
        int g = batch[v];
        float xv = x[(size_t)v * C_DIM + lane];
        float xq = xv * xv;
        s0 += (g==0)?xv:0.0f;  q0 += (g==0)?xq:0.0f;
        s1 += (g==1)?xv:0.0f;  q1 += (g==1)?xq:0.0f;
        s2 += (g==2)?xv:0.0f;  q2 += (g==2)?xq:0.0f;
        s3 += (g==3)?xv:0.0f;  q3 += (g==3)?xq:0.0f;
        if (lane == 0) {
            c0 += (g==0)?1.0f:0.0f; c1 += (g==1)?1.0f:0.0f;
            c2 += (g==2)?1.0f:0.0f; c3 += (g==3)?1.0f:0.0f;
        }
    }
    __shared__ float red_s[G_NUM*C_DIM];
    __shared__ float red_q[G_NUM*C_DIM];
    __shared__ float red_c[G_NUM];
    for (int i = threadIdx.x; i < G_NUM*C_DIM; i += 256) { red_s[i]=0.0f; red_q[i]=0.0f; }
    if (threadIdx.x < G_NUM) red_c[threadIdx.x] = 0.0f;
    __syncthreads();
    atomicAdd(&red_s[0*64+lane], s0); atomicAdd(&red_q[0*64+lane], q0);
    atomicAdd(&red_s[1*64+lane], s1); atomicAdd(&red_q[1*64+lane], q1);
    atomicAdd(&red_s[2*64+lane], s2); atomicAdd(&red_q[2*64+lane], q2);
    atomicAdd(&red_s[3*64+lane], s3); atomicAdd(&red_q[3*64+lane], q3);
    if (lane == 0) {
        atomicAdd(&red_c[0], c0); atomicAdd(&red_c[1], c1);
        atomicAdd(&red_c[2], c2); atomicAdd(&red_c[3], c3);
    }
    __syncthreads();
    atomicAdd(&sum1[threadIdx.x],   red_s[threadIdx.x]);
    atomicAdd(&sumsq1[threadIdx.x], red_q[threadIdx.x]);
    if (threadIdx.x < G_NUM) atomicAdd(&cnt[threadIdx.x], red_c[threadIdx.x]);
}

// ---------------------------------------------------------------------------
// Kernel 2: fold GraphNorm into per-(g,c) affine: y = x*scale + shift
// var = E[x^2] - 2*ms*mean^2 + ms^2*mean^2   (centered = x - mean*ms)
// ---------------------------------------------------------------------------
__global__ __launch_bounds__(256) void k_params(const float* __restrict__ sum,
                                                const float* __restrict__ sumsq,
                                                const float* __restrict__ cnt,
                                                const float* __restrict__ w,
                                                const float* __restrict__ b,
                                                const float* __restrict__ ms,
                                                float* __restrict__ scale,
                                                float* __restrict__ shift) {
    int t = threadIdx.x;            // t = g*64 + c
    int g = t >> 6, c = t & 63;
    float n    = cnt[g];
    float mean = sum[t] / n;
    float msq  = sumsq[t] / n;
    float m    = ms[c];
    float var  = msq - 2.0f*m*mean*mean + m*m*mean*mean;
    float inv  = rsqrtf(var + EPS_GN);
    float sc   = w[c] * inv;
    scale[t] = sc;
    shift[t] = b[c] - mean * m * sc;
}

// ---------------------------------------------------------------------------
// Kernel 3: scatter-max of normalized source features onto destinations
// wave-per-edge, lane-per-channel. h recomputed on the fly (h never stored).
// ---------------------------------------------------------------------------
__global__ __launch_bounds__(256) void k_scatter(const float* __restrict__ x,
                                                 const int* __restrict__ ei,
                                                 const int* __restrict__ batch,
                                                 const float* __restrict__ scale1,
                                                 const float* __restrict__ shift1,
                                                 unsigned* __restrict__ agg) {
    __shared__ float sc[G_NUM*C_DIM], sh[G_NUM*C_DIM];
    sc[threadIdx.x] = scale1[threadIdx.x];
    sh[threadIdx.x] = shift1[threadIdx.x];
    __syncthreads();
    int lane = threadIdx.x & 63;
    int wid  = threadIdx.x >> 6;
    int stride = gridDim.x * 4;
    for (int e = blockIdx.x * 4 + wid; e < E_EDGES; e += stride) {
        int s = ei[e];
        int d = ei[E_EDGES + e];
        int g = batch[s];
        float xv = x[(size_t)s * C_DIM + lane];
        int   p  = (g << 6) | lane;
        float hv = fmaf(xv, sc[p], sh[p]);
        unsigned key = enc_f(hv);
        unsigned* addr = agg + ((size_t)d * C_DIM + lane);
        // stale read is safe: values only grow, a stale value is <= current,
        // so we may only do a redundant atomic, never skip a needed one.
        unsigned cur = *addr;
        if (key > cur) atomicMax(addr, key);
    }
}

// ---------------------------------------------------------------------------
// Kernel 4: fused SAGE linear + residual + ReLU + norm2 statistics
// wave-per-row; weights staged in LDS; writes pre-norm result to d_out.
// ---------------------------------------------------------------------------
__global__ __launch_bounds__(256) void k_sage(const float* __restrict__ x,
                                              const int* __restrict__ batch,
                                              const unsigned* __restrict__ agg,
                                              const float* __restrict__ Wl,
                                              const float* __restrict__ bl,
                                              const float* __restrict__ Wr,
                                              const float* __restrict__ scale1,
                                              const float* __restrict__ shift1,
                                              float* __restrict__ r_out,
                                              float* __restrict__ sum2,
                                              float* __restrict__ sumsq2) {
    __shared__ float lWl[C_DIM*C_DIM];   // 16 KB, layout W[k][c]
    __shared__ float lWr[C_DIM*C_DIM];   // 16 KB
    __shared__ float sc[G_NUM*C_DIM], sh[G_NUM*C_DIM];
    __shared__ float la[4][C_DIM], lh[4][C_DIM];
    __shared__ float red_s[G_NUM*C_DIM], red_q[G_NUM*C_DIM];

    {   // vectorized weight staging
        const float4* wl4 = (const float4*)Wl;
        const float4* wr4 = (const float4*)Wr;
        float4* l4 = (float4*)lWl;
        float4* r4 = (float4*)lWr;
        for (int i = threadIdx.x; i < C_DIM*C_DIM/4; i += 256) { l4[i] = wl4[i]; r4[i] = wr4[i]; }
    }
    sc[threadIdx.x] = scale1[threadIdx.x];
    sh[threadIdx.x] = shift1[threadIdx.x];
    red_s[threadIdx.x] = 0.0f; red_q[threadIdx.x] = 0.0f;
    __syncthreads();

    int lane = threadIdx.x & 63;
    int wid  = threadIdx.x >> 6;
    float blv = bl[lane];
    float s0=0,s1=0,s2=0,s3=0,q0=0,q1=0,q2=0,q3=0;
    int stride = gridDim.x * 4;

    for (int v = blockIdx.x * 4 + wid; v < V_NODES; v += stride) {
        int g = batch[v];
        float xv = x[(size_t)v * C_DIM + lane];
        int   p  = (g << 6) | lane;
        float hv = fmaf(xv, sc[p], sh[p]);
        unsigned k = agg[(size_t)v * C_DIM + lane];
        float av = (k == 0u) ? 0.0f : dec_f(k);
        la[wid][lane] = av;
        lh[wid][lane] = hv;
        __builtin_amdgcn_wave_barrier();   // wave-internal LDS RAW; same-wave DS ops are in-order
        float acc = blv;
        #pragma unroll 16
        for (int kk = 0; kk < C_DIM; kk++) {
            acc = fmaf(la[wid][kk], lWl[kk*C_DIM + lane], acc);
            acc = fmaf(lh[wid][kk], lWr[kk*C_DIM + lane], acc);
        }
        __builtin_amdgcn_wave_barrier();
        float rv = fmaxf(xv + acc, 0.0f);
        r_out[(size_t)v * C_DIM + lane] = rv;
        float rq = rv * rv;
        s0 += (g==0)?rv:0.0f;  q0 += (g==0)?rq:0.0f;
        s1 += (g==1)?rv:0.0f;  q1 += (g==1)?rq:0.0f;
        s2 += (g==2)?rv:0.0f;  q2 += (g==2)?rq:0.0f;
        s3 += (g==3)?rv:0.0f;  q3 += (g==3)?rq:0.0f;
    }

    atomicAdd(&red_s[0*64+lane], s0); atomicAdd(&red_q[0*64+lane], q0);
    atomicAdd(&red_s[1*64+lane], s1); atomicAdd(&red_q[1*64+lane], q1);
    atomicAdd(&red_s[2*64+lane], s2); atomicAdd(&red_q[2*64+lane], q2);
    atomicAdd(&red_s[3*64+lane], s3); atomicAdd(&red_q[3*64+lane], q3);
    __syncthreads();
    atomicAdd(&sum2[threadIdx.x],   red_s[threadIdx.x]);
    atomicAdd(&sumsq2[threadIdx.x], red_q[threadIdx.x]);
}

// ---------------------------------------------------------------------------
// Kernel 5: in-place final GraphNorm affine on d_out (float4 vectorized)
// ---------------------------------------------------------------------------
__global__ __launch_bounds__(256) void k_final(float* __restrict__ out,
                                               const int* __restrict__ batch,
                                               const float* __restrict__ scale2,
                                               const float* __restrict__ shift2) {
    __shared__ float sc[G_NUM*C_DIM], sh[G_NUM*C_DIM];
    sc[threadIdx.x] = scale2[threadIdx.x];
    sh[threadIdx.x] = shift2[threadIdx.x];
    __syncthreads();
    const int total = V_NODES * (C_DIM/4);     // float4 chunks
    int stride = gridDim.x * 256;
    float4* o4 = (float4*)out;
    for (int i = blockIdx.x * 256 + threadIdx.x; i < total; i += stride) {
        int v  = i >> 4;
        int c4 = (i & 15) << 2;
        int g  = batch[v];
        int p  = (g << 6) | c4;
        float4 val = o4[i];
        val.x = fmaf(val.x, sc[p],   sh[p]);
        val.y = fmaf(val.y, sc[p+1], sh[p+1]);
        val.z = fmaf(val.z, sc[p+2], sh[p+2]);
        val.w = fmaf(val.w, sc[p+3], sh[p+3]);
        o4[i] = val;
    }
}

// ---------------------------------------------------------------------------
extern "C" void kernel_launch(void* const* d_in, const int* in_sizes, int n_in,
                              void* d_out, int out_size, void* d_ws, size_t ws_size,
                              hipStream_t stream) {
    const float* x     = (const float*)d_in[0];
    const int*   ei    = (const int*)  d_in[1];   // [2,E] int32 per harness contract
    const int*   batch = (const int*)  d_in[2];
    const float* n1w   = (const float*)d_in[3];
    const float* n1b   = (const float*)d_in[4];
    const float* n1ms  = (const float*)d_in[5];
    const float* Wl    = (const float*)d_in[6];
    const float* blv   = (const float*)d_in[7];
    const float* Wr    = (const float*)d_in[8];
    const float* n2w   = (const float*)d_in[9];
    const float* n2b   = (const float*)d_in[10];
    const float* n2ms  = (const float*)d_in[11];
    float* out = (float*)d_out;

    // workspace layout
    unsigned* agg  = (unsigned*)d_ws;                                   // V*C uints (84 MB)
    float* stats   = (float*)((char*)d_ws + (size_t)V_NODES*C_DIM*4);
    float* sum1    = stats;          // 256
    float* sumsq1  = stats + 256;    // 256
    float* sum2    = stats + 512;    // 256
    float* sumsq2  = stats + 768;    // 256
    float* cnt     = stats + 1024;   // 4 (+pad to 1152)
    float* scale1  = stats + 1152;
    float* shift1  = stats + 1408;
    float* scale2  = stats + 1664;
    float* shift2  = stats + 1920;   // end: 2176 floats

    hipMemsetAsync(stats, 0, 1152 * sizeof(float), stream);                        // zero accumulators
    hipMemsetAsync(agg, 0, (size_t)V_NODES * C_DIM * sizeof(unsigned), stream);    // key 0 == "no edge"

    k_stats1 <<<512, 256, 0, stream>>>(x, batch, sum1, sumsq1, cnt);
    k_params <<<1,   256, 0, stream>>>(sum1, sumsq1, cnt, n1w, n1b, n1ms, scale1, shift1);
    k_scatter<<<8192,256, 0, stream>>>(x, ei, batch, scale1, shift1, agg);
    k_sage   <<<2048,256, 0, stream>>>(x, batch, agg, Wl, blv, Wr, scale1, shift1, out, sum2, sumsq2);
    k_params <<<1,   256, 0, stream>>>(sum2, sumsq2, cnt, n2w, n2b, n2ms, scale2, shift2);
    k_final  <<<2048,256, 0, stream>>>(out, batch, scale2, shift2);
}

// Round 2
// 623.454 us; speedup vs baseline: 1.1535x; 1.1535x over previous
//
#include <hip/hip_runtime.h>

#define V_NODES 327696
#define E_EDGES 1966080
#define C_DIM   64
#define G_NUM   4
#define EPS_GN  1e-5f
#define NB_SCAN 1281          // ceil(V/256)
#define CH_SCAN2 6            // ceil(NB_SCAN/256)

typedef short bf16x8 __attribute__((ext_vector_type(8)));
typedef float f32x4  __attribute__((ext_vector_type(4)));
typedef unsigned uintx4 __attribute__((ext_vector_type(4)));

__device__ __forceinline__ unsigned short f2bf(float f) {   // RNE f32 -> bf16
    unsigned u = __float_as_uint(f);
    return (unsigned short)((u + 0x7FFFu + ((u >> 16) & 1u)) >> 16);
}

// ---------------------------------------------------------------------------
// Kernel 1: per-(graph,channel) sum / sumsq / count over x
// ---------------------------------------------------------------------------
__global__ __launch_bounds__(256) void k_stats1(const float* __restrict__ x,
                                                const int* __restrict__ batch,
                                                float* __restrict__ sum1,
                                                float* __restrict__ sumsq1,
                                                float* __restrict__ cnt) {
    int lane = threadIdx.x & 63;
    int wid  = threadIdx.x >> 6;
    float s0=0,s1=0,s2=0,s3=0,q0=0,q1=0,q2=0,q3=0;
    float c0=0,c1=0,c2=0,c3=0;
    int stride = gridDim.x * 4;
    for (int v = blockIdx.x * 4 + wid; v < V_NODES; v += stride) {
        int g = batch[v];
        float xv = x[(size_t)v * C_DIM + lane];
        float xq = xv * xv;
        s0 += (g==0)?xv:0.0f;  q0 += (g==0)?xq:0.0f;
        s1 += (g==1)?xv:0.0f;  q1 += (g==1)?xq:0.0f;
        s2 += (g==2)?xv:0.0f;  q2 += (g==2)?xq:0.0f;
        s3 += (g==3)?xv:0.0f;  q3 += (g==3)?xq:0.0f;
        if (lane == 0) {
            c0 += (g==0)?1.0f:0.0f; c1 += (g==1)?1.0f:0.0f;
            c2 += (g==2)?1.0f:0.0f; c3 += (g==3)?1.0f:0.0f;
        }
    }
    __shared__ float red_s[G_NUM*C_DIM];
    __shared__ float red_q[G_NUM*C_DIM];
    __shared__ float red_c[G_NUM];
    for (int i = threadIdx.x; i < G_NUM*C_DIM; i += 256) { red_s[i]=0.0f; red_q[i]=0.0f; }
    if (threadIdx.x < G_NUM) red_c[threadIdx.x] = 0.0f;
    __syncthreads();
    atomicAdd(&red_s[0*64+lane], s0); atomicAdd(&red_q[0*64+lane], q0);
    atomicAdd(&red_s[1*64+lane], s1); atomicAdd(&red_q[1*64+lane], q1);
    atomicAdd(&red_s[2*64+lane], s2); atomicAdd(&red_q[2*64+lane], q2);
    atomicAdd(&red_s[3*64+lane], s3); atomicAdd(&red_q[3*64+lane], q3);
    if (lane == 0) {
        atomicAdd(&red_c[0], c0); atomicAdd(&red_c[1], c1);
        atomicAdd(&red_c[2], c2); atomicAdd(&red_c[3], c3);
    }
    __syncthreads();
    atomicAdd(&sum1[threadIdx.x],   red_s[threadIdx.x]);
    atomicAdd(&sumsq1[threadIdx.x], red_q[threadIdx.x]);
    if (threadIdx.x < G_NUM) atomicAdd(&cnt[threadIdx.x], red_c[threadIdx.x]);
}

// ---------------------------------------------------------------------------
// Kernel 2: fold GraphNorm into per-(g,c) affine
// ---------------------------------------------------------------------------
__global__ __launch_bounds__(256) void k_params(const float* __restrict__ sum,
                                                const float* __restrict__ sumsq,
                                                const float* __restrict__ cnt,
                                                const float* __restrict__ w,
                                                const float* __restrict__ b,
                                                const float* __restrict__ ms,
                                                float* __restrict__ scale,
                                                float* __restrict__ shift) {
    int t = threadIdx.x;            // t = g*64 + c
    int g = t >> 6, c = t & 63;
    float n    = cnt[g];
    float mean = sum[t] / n;
    float msq  = sumsq[t] / n;
    float m    = ms[c];
    float var  = msq - 2.0f*m*mean*mean + m*m*mean*mean;
    float inv  = rsqrtf(var + EPS_GN);
    float sc   = w[c] * inv;
    scale[t] = sc;
    shift[t] = b[c] - mean * m * sc;
}

// ---------------------------------------------------------------------------
// Kernel 3: h_bf16[v][c] = bf16(x*scale1 + shift1)   (norm1 applied once)
// ---------------------------------------------------------------------------
__global__ __launch_bounds__(256) void k_h(const float* __restrict__ x,
                                           const int* __restrict__ batch,
                                           const float* __restrict__ scale1,
                                           const float* __restrict__ shift1,
                                           unsigned short* __restrict__ h) {
    __shared__ float sc[256], sh[256];
    sc[threadIdx.x] = scale1[threadIdx.x];
    sh[threadIdx.x] = shift1[threadIdx.x];
    __syncthreads();
    const int total = V_NODES * 16;           // float4 chunks
    int stride = gridDim.x * 256;
    const float4* x4 = (const float4*)x;
    ushort4* h4 = (ushort4*)h;
    for (int i = blockIdx.x * 256 + threadIdx.x; i < total; i += stride) {
        int v  = i >> 4;
        int c4 = (i & 15) << 2;
        int g  = batch[v];
        int p  = (g << 6) | c4;
        float4 val = x4[i];
        ushort4 o;
        o.x = f2bf(fmaf(val.x, sc[p],   sh[p]));
        o.y = f2bf(fmaf(val.y, sc[p+1], sh[p+1]));
        o.z = f2bf(fmaf(val.z, sc[p+2], sh[p+2]));
        o.w = f2bf(fmaf(val.w, sc[p+3], sh[p+3]));
        h4[i] = o;
    }
}

// ---------------------------------------------------------------------------
// CSR build: histogram -> 2-level exclusive scan -> fill
// ---------------------------------------------------------------------------
__global__ __launch_bounds__(256) void k_hist(const int* __restrict__ ei,
                                              int* __restrict__ hist) {
    int stride = gridDim.x * 256;
    for (int e = blockIdx.x * 256 + threadIdx.x; e < E_EDGES; e += stride)
        atomicAdd(&hist[ei[E_EDGES + e]], 1);
}

__global__ __launch_bounds__(256) void k_scan1(const int* __restrict__ hist,
                                               int* __restrict__ bsum) {
    __shared__ int s[256];
    int i = blockIdx.x * 256 + threadIdx.x;
    s[threadIdx.x] = (i < V_NODES) ? hist[i] : 0;
    __syncthreads();
    for (int off = 128; off > 0; off >>= 1) {
        if (threadIdx.x < off) s[threadIdx.x] += s[threadIdx.x + off];
        __syncthreads();
    }
    if (threadIdx.x == 0) bsum[blockIdx.x] = s[0];
}

__global__ __launch_bounds__(256) void k_scan2(int* __restrict__ bsum) {
    __shared__ int s[256];
    int t = threadIdx.x;
    int loc[CH_SCAN2];
    int mysum = 0;
    #pragma unroll
    for (int j = 0; j < CH_SCAN2; j++) {
        int idx = t * CH_SCAN2 + j;
        loc[j] = (idx < NB_SCAN) ? bsum[idx] : 0;
        mysum += loc[j];
    }
    s[t] = mysum;
    __syncthreads();
    for (int off = 1; off < 256; off <<= 1) {      // Hillis-Steele inclusive
        int tmp = (t >= off) ? s[t - off] : 0;
        __syncthreads();
        s[t] += tmp;
        __syncthreads();
    }
    int ex = s[t] - mysum;                          // exclusive prefix
    #pragma unroll
    for (int j = 0; j < CH_SCAN2; j++) {
        int idx = t * CH_SCAN2 + j;
        if (idx < NB_SCAN) { bsum[idx] = ex; ex += loc[j]; }
    }
}

__global__ __launch_bounds__(256) void k_scan3(const int* __restrict__ hist,
                                               const int* __restrict__ bsum,
                                               int* __restrict__ offs,
                                               int* __restrict__ cursor) {
    __shared__ int s[256];
    int t = threadIdx.x;
    int i = blockIdx.x * 256 + t;
    int v = (i < V_NODES) ? hist[i] : 0;
    s[t] = v;
    __syncthreads();
    for (int off = 1; off < 256; off <<= 1) {
        int tmp = (t >= off) ? s[t - off] : 0;
        __syncthreads();
        s[t] += tmp;
        __syncthreads();
    }
    int ex = s[t] - v + bsum[blockIdx.x];
    if (i < V_NODES) { offs[i] = ex; cursor[i] = ex; }
    if (i == 0) offs[V_NODES] = E_EDGES;
}

__global__ __launch_bounds__(256) void k_fill(const int* __restrict__ ei,
                                              int* __restrict__ cursor,
                                              int* __restrict__ slots) {
    int stride = gridDim.x * 256;
    for (int e = blockIdx.x * 256 + threadIdx.x; e < E_EDGES; e += stride) {
        int sdx = ei[e];
        int d   = ei[E_EDGES + e];
        int p   = atomicAdd(&cursor[d], 1);
        slots[p] = sdx;
    }
}

// ---------------------------------------------------------------------------
// Kernel 4: fused gather-max + dual GEMM (MFMA bf16) + residual/ReLU + stats2
// wave-per-16-row-tile. Gather pulls A-fragments directly in MFMA layout:
// lane l owns row (l&15), k-slice ((l>>4)*8 .. +8) for each of 2 k-steps.
// ---------------------------------------------------------------------------
__global__ __launch_bounds__(256) void k_sage(const unsigned short* __restrict__ h,
                                              const float* __restrict__ x,
                                              const int* __restrict__ batch,
                                              const int* __restrict__ offs,
                                              const int* __restrict__ slots,
                                              const unsigned short* __restrict__ WlT,
                                              const unsigned short* __restrict__ WrT,
                                              const float* __restrict__ bl,
                                              float* __restrict__ out,
                                              float* __restrict__ sum2,
                                              float* __restrict__ sumsq2) {
    __shared__ float red_s[G_NUM*C_DIM], red_q[G_NUM*C_DIM];
    red_s[threadIdx.x] = 0.0f; red_q[threadIdx.x] = 0.0f;
    __syncthreads();

    const int lane = threadIdx.x & 63;
    const int wid  = threadIdx.x >> 6;
    const int lg   = lane >> 4;        // lane group 0..3 -> k-slice / out-row-group
    const int lr   = lane & 15;        // row (A) / col (B,C)

    // B fragments (weights, pre-transposed to WT[c][k] bf16), held in regs.
    // frag[kst][cb]: col = cb*16+lr, k = kst*32 + lg*8 + j  (8 contiguous)
    bf16x8 wl[2][4], wr[2][4];
    #pragma unroll
    for (int kst = 0; kst < 2; kst++)
        #pragma unroll
        for (int cb = 0; cb < 4; cb++) {
            int off = (cb*16 + lr)*64 + kst*32 + lg*8;
            wl[kst][cb] = *(const bf16x8*)(WlT + off);
            wr[kst][cb] = *(const bf16x8*)(WrT + off);
        }
    float blv[4];
    #pragma unroll
    for (int cb = 0; cb < 4; cb++) blv[cb] = bl[cb*16 + lr];

    const int nTiles = V_NODES / 16;            // 20481, exact
    const int waves  = gridDim.x * 4;
    for (int tile = blockIdx.x*4 + wid; tile < nTiles; tile += waves) {
        const int rbase = tile * 16;
        const int myrow = rbase + lr;
        // ---- gather-max into A-layout registers ----
        int st = offs[myrow];
        int en = offs[myrow + 1];
        float m0[8], m1[8];
        #pragma unroll
        for (int j = 0; j < 8; j++) { m0[j] = -3.0e38f; m1[j] = -3.0e38f; }
        for (int i = st; ; i++) {
            bool act = i < en;
            if (__ballot(act) == 0ull) break;
            if (act) {
                int src = slots[i];
                const unsigned short* hp = h + (size_t)src * C_DIM;
                uintx4 u0 = *(const uintx4*)(hp + lg*8);
                uintx4 u1 = *(const uintx4*)(hp + 32 + lg*8);
                #pragma unroll
                for (int w = 0; w < 4; w++) {
                    m0[2*w]   = fmaxf(m0[2*w],   __uint_as_float(u0[w] << 16));
                    m0[2*w+1] = fmaxf(m0[2*w+1], __uint_as_float(u0[w] & 0xFFFF0000u));
                    m1[2*w]   = fmaxf(m1[2*w],   __uint_as_float(u1[w] << 16));
                    m1[2*w+1] = fmaxf(m1[2*w+1], __uint_as_float(u1[w] & 0xFFFF0000u));
                }
            }
        }
        bool has = en > st;                    // no in-edges -> agg = 0
        bf16x8 a_agg0, a_agg1;
        #pragma unroll
        for (int j = 0; j < 8; j++) {
            a_agg0[j] = (short)f2bf(has ? m0[j] : 0.0f);
            a_agg1[j] = (short)f2bf(has ? m1[j] : 0.0f);
        }
        // h (root) fragments for this row
        const unsigned short* hr = h + (size_t)myrow * C_DIM;
        bf16x8 a_h0 = *(const bf16x8*)(hr + lg*8);
        bf16x8 a_h1 = *(const bf16x8*)(hr + 32 + lg*8);

        // ---- dual GEMM: acc = agg@Wl + h@Wr ----
        f32x4 acc[4];
        #pragma unroll
        for (int cb = 0; cb < 4; cb++) acc[cb] = (f32x4){0.f,0.f,0.f,0.f};
        #pragma unroll
        for (int cb = 0; cb < 4; cb++) {
            acc[cb] = __builtin_amdgcn_mfma_f32_16x16x32_bf16(a_agg0, wl[0][cb], acc[cb], 0,0,0);
            acc[cb] = __builtin_amdgcn_mfma_f32_16x16x32_bf16(a_agg1, wl[1][cb], acc[cb], 0,0,0);
            acc[cb] = __builtin_amdgcn_mfma_f32_16x16x32_bf16(a_h0,   wr[0][cb], acc[cb], 0,0,0);
            acc[cb] = __builtin_amdgcn_mfma_f32_16x16x32_bf16(a_h1,   wr[1][cb], acc[cb], 0,0,0);
        }
        // ---- epilogue: bias + residual + ReLU + write + norm2 stats ----
        // C layout: row = rbase + lg*4 + r, col = cb*16 + lr
        #pragma unroll
        for (int r = 0; r < 4; r++) {
            int row = rbase + lg*4 + r;
            int g   = batch[row];
            #pragma unroll
            for (int cb = 0; cb < 4; cb++) {
                int col = cb*16 + lr;
                float xv = x[(size_t)row * C_DIM + col];
                float o  = fmaxf(xv + acc[cb][r] + blv[cb], 0.0f);
                out[(size_t)row * C_DIM + col] = o;
                int p = (g << 6) | col;
                atomicAdd(&red_s[p], o);
                atomicAdd(&red_q[p], o * o);
            }
        }
    }
    __syncthreads();
    atomicAdd(&sum2[threadIdx.x],   red_s[threadIdx.x]);
    atomicAdd(&sumsq2[threadIdx.x], red_q[threadIdx.x]);
}

// ---------------------------------------------------------------------------
// Kernel 5: weight transpose + bf16 cast (WT[c][k] = bf16(W[k][c]))
// ---------------------------------------------------------------------------
__global__ __launch_bounds__(256) void k_wt(const float* __restrict__ Wl,
                                            const float* __restrict__ Wr,
                                            unsigned short* __restrict__ WlT,
                                            unsigned short* __restrict__ WrT) {
    int t = blockIdx.x * 256 + threadIdx.x;
    if (t < C_DIM * C_DIM) {
        int k = t >> 6, c = t & 63;
        WlT[c*64 + k] = f2bf(Wl[t]);
        WrT[c*64 + k] = f2bf(Wr[t]);
    }
}

// ---------------------------------------------------------------------------
// Kernel 6: in-place final GraphNorm affine on d_out (float4 vectorized)
// ---------------------------------------------------------------------------
__global__ __launch_bounds__(256) void k_final(float* __restrict__ out,
                                               const int* __restrict__ batch,
                                               const float* __restrict__ scale2,
                                               const float* __restrict__ shift2) {
    __shared__ float sc[256], sh[256];
    sc[threadIdx.x] = scale2[threadIdx.x];
    sh[threadIdx.x] = shift2[threadIdx.x];
    __syncthreads();
    const int total = V_NODES * 16;
    int stride = gridDim.x * 256;
    float4* o4 = (float4*)out;
    for (int i = blockIdx.x * 256 + threadIdx.x; i < total; i += stride) {
        int v  = i >> 4;
        int c4 = (i & 15) << 2;
        int g  = batch[v];
        int p  = (g << 6) | c4;
        float4 val = o4[i];
        val.x = fmaf(val.x, sc[p],   sh[p]);
        val.y = fmaf(val.y, sc[p+1], sh[p+1]);
        val.z = fmaf(val.z, sc[p+2], sh[p+2]);
        val.w = fmaf(val.w, sc[p+3], sh[p+3]);
        o4[i] = val;
    }
}

// ---------------------------------------------------------------------------
extern "C" void kernel_launch(void* const* d_in, const int* in_sizes, int n_in,
                              void* d_out, int out_size, void* d_ws, size_t ws_size,
                              hipStream_t stream) {
    const float* x     = (const float*)d_in[0];
    const int*   ei    = (const int*)  d_in[1];
    const int*   batch = (const int*)  d_in[2];
    const float* n1w   = (const float*)d_in[3];
    const float* n1b   = (const float*)d_in[4];
    const float* n1ms  = (const float*)d_in[5];
    const float* Wl    = (const float*)d_in[6];
    const float* blv   = (const float*)d_in[7];
    const float* Wr    = (const float*)d_in[8];
    const float* n2w   = (const float*)d_in[9];
    const float* n2b   = (const float*)d_in[10];
    const float* n2ms  = (const float*)d_in[11];
    float* out = (float*)d_out;

    // ---- workspace layout (≈54 MB; round-1 proved ws_size ≥ 84 MB) ----
    char* w = (char*)d_ws;
    unsigned short* h   = (unsigned short*)w;  w += (size_t)V_NODES * C_DIM * 2;  // 42 MB
    int* slots          = (int*)w;             w += (size_t)E_EDGES * 4;          // 8 MB
    int* hist           = (int*)w;             w += (size_t)V_NODES * 4;
    int* offs           = (int*)w;             w += (size_t)(V_NODES + 1) * 4 + 12;
    int* cursor         = (int*)w;             w += (size_t)V_NODES * 4;
    int* bsum           = (int*)w;             w += 1536 * 4;
    unsigned short* WlT = (unsigned short*)w;  w += C_DIM * C_DIM * 2;
    unsigned short* WrT = (unsigned short*)w;  w += C_DIM * C_DIM * 2;
    float* stats  = (float*)w;
    float* sum1   = stats;          // 256
    float* sumsq1 = stats + 256;    // 256
    float* sum2   = stats + 512;    // 256
    float* sumsq2 = stats + 768;    // 256
    float* cnt    = stats + 1024;   // 4 (pad 64)
    float* scale1 = stats + 1088;
    float* shift1 = stats + 1344;
    float* scale2 = stats + 1600;
    float* shift2 = stats + 1856;   // end 2112 floats

    hipMemsetAsync(stats, 0, 1088 * sizeof(float), stream);   // sums + cnt
    hipMemsetAsync(hist, 0, (size_t)V_NODES * sizeof(int), stream);

    k_stats1<<<1024, 256, 0, stream>>>(x, batch, sum1, sumsq1, cnt);
    k_hist  <<<1024, 256, 0, stream>>>(ei, hist);
    k_wt    <<<16,   256, 0, stream>>>(Wl, Wr, WlT, WrT);
    k_params<<<1,    256, 0, stream>>>(sum1, sumsq1, cnt, n1w, n1b, n1ms, scale1, shift1);
    k_h     <<<2048, 256, 0, stream>>>(x, batch, scale1, shift1, h);
    k_scan1 <<<NB_SCAN, 256, 0, stream>>>(hist, bsum);
    k_scan2 <<<1,    256, 0, stream>>>(bsum);
    k_scan3 <<<NB_SCAN, 256, 0, stream>>>(hist, bsum, offs, cursor);
    k_fill  <<<1024, 256, 0, stream>>>(ei, cursor, slots);
    k_sage  <<<2048, 256, 0, stream>>>(h, x, batch, offs, slots, WlT, WrT, blv,
                                       out, sum2, sumsq2);
    k_params<<<1,    256, 0, stream>>>(sum2, sumsq2, cnt, n2w, n2b, n2ms, scale2, shift2);
    k_final <<<2048, 256, 0, stream>>>(out, batch, scale2, shift2);
}